// Round 9
// baseline (165.014 us; speedup 1.0000x reference)
//
#include <hip/hip_runtime.h>
#include <hip/hip_bf16.h>
#include <stdint.h>

// RecNN: B=2048, L=256, F=64, H=128. One WG (256 thr, 4 waves) per 8 batch
// elems. Subtree-BFS(16 leaves) + DFS over 16 roots. Each wave owns 32 output
// cols (2 nt frags, 112 weight VGPRs) so one A-read feeds 2 MFMAs and A-panel
// read redundancy is 4x (vs 8x at 16 cols/wave) — LDS read pipe was ~80% busy
// in round 8. 256 thr / 1 wave-per-SIMD doubles the arch-VGPR budget: the
// allocator caps at 128 arch VGPRs for 2 waves/SIMD (rounds 2/3/5/7 all
// spilled at 112+ws there; round 1 at 256 thr fit cleanly).

#define B_TOT 2048
#define LL    256
#define FF    64
#define HH    128
#define LF    (LL*FF)
#define BC    8
#define NTHR  256
#define NSUB  16

typedef __bf16 v8bf __attribute__((ext_vector_type(8)));
typedef float  v4f  __attribute__((ext_vector_type(4)));

// ---- LDS layout (bytes) ----
#define XB_OFF    0        // [128]x128B bf16 swz128: leaf x            16384
#define XB2_OFF   16384    // [128]x128B bf16 swz128: data1..4 + root   16384
#define DB_OFF    32768    // [64]x256B f32 swz256: data1 / data3       16384
#define DB2_OFF   49152    // [48]x256B f32 swz256: data2 / data4       12288
#define HA_OFF    61440    // [128]x256B bf16 swz256: h0 / h2           32768
#define HB_OFF    94208    // [64]x256B bf16: h1 / h3 / z2              16384
#define U_OFF     110592   // [64]x256B bf16: u / z1                    16384
#define HCUR_OFF  126976   // [16]x256B bf16: root h                     4096
#define DCUR_OFF  131072   // [8]x256B f32: root data                    2048
#define HSTK_OFF  133120   // 4 x 4096                                  16384
#define DSTK_OFF  149504   // 4 x 2048                                   8192
#define BIAS_OFF  157696   // 4 x 512B f32                               2048
#define LDS_BYTES 159744

__device__ __forceinline__ uint32_t swz256(uint32_t row, uint32_t b){
    return (row*256u + b) ^ ((row & 7u) << 4);
}
__device__ __forceinline__ uint32_t swz128(uint32_t row, uint32_t b){
    return (row*128u + b) ^ ((row & 7u) << 4);
}
__device__ __forceinline__ v4f mfma16(v8bf a, v8bf b, v4f c){
    return __builtin_amdgcn_mfma_f32_16x16x32_bf16(a, b, c, 0, 0, 0);
}
__device__ __forceinline__ uint32_t pk2(float a, float b){
    uint32_t lo = (uint32_t)__builtin_bit_cast(unsigned short, (__bf16)a);
    uint32_t hi = (uint32_t)__builtin_bit_cast(unsigned short, (__bf16)b);
    return lo | (hi << 16);
}
__device__ __forceinline__ uint2 pk4(v4f v){
    return make_uint2(pk2(v[0], v[1]), pk2(v[2], v[3]));
}

// B-fragment: lane holds col n0+(l&15), k = k0 + 8*(l>>4) + j. W row-major [K][128] f32.
__device__ __forceinline__ v8bf ldW(const float* __restrict__ W, int k0, int n0){
    uint32_t lane = threadIdx.x & 63u;
    int n = n0 + (int)(lane & 15u);
    int k = k0 + (int)((lane >> 4) << 3);
    v8bf r;
    #pragma unroll
    for (int j = 0; j < 8; ++j) r[j] = (__bf16)W[(k + j)*HH + n];
    return r;
}

// A-frag from bf16 64-col panel (swz128). rows >= realrows -> 0.
__device__ __forceinline__ v8bf ldX(const char* xb, uint32_t row0, uint32_t mt,
                                    uint32_t kf, uint32_t realrows){
    uint32_t lane = threadIdx.x & 63u;
    uint32_t rl = mt*16u + (lane & 15u);
    if (rl >= realrows){
        v8bf z;
        #pragma unroll
        for (int j = 0; j < 8; ++j) z[j] = (__bf16)0.0f;
        return z;
    }
    return *reinterpret_cast<const v8bf*>(xb + swz128(row0 + rl, kf*64u + ((lane>>4)<<4)));
}

// A-frag from 16-row bf16 buffer (swz256), row = lane&15 (merge/head GEMMs)
__device__ __forceinline__ v8bf ldH(const char* buf, uint32_t kf){
    uint32_t lane = threadIdx.x & 63u;
    return *reinterpret_cast<const v8bf*>(buf + swz256(lane & 15u,
                                          kf*64u + ((lane>>4)<<4)));
}

// A-frag for subtree nl GEMM (node-major): out tile mt -> nodes 2mt,2mt+1;
// children rows 32mt+16*(r>=8)+8*sec+(r&7); u row 16mt+r.
__device__ __forceinline__ v8bf ldA_nl(const char* hprev, const char* ub,
                                       uint32_t mt, uint32_t kf){
    uint32_t lane = threadIdx.x & 63u, r = lane & 15u;
    uint32_t kb = (kf & 3u)*64u + ((lane >> 4) << 4);
    uint32_t sec = kf >> 2;
    if (sec < 2u){
        uint32_t row = mt*32u + ((r >> 3) << 4) + sec*8u + (r & 7u);
        return *reinterpret_cast<const v8bf*>(hprev + swz256(row, kb));
    }
    return *reinterpret_cast<const v8bf*>(ub + swz256(mt*16u + r, kb));
}

// Epilogue: relu(acc+bias) -> bf16 swz256 LDS at rows row0+(l>>4)*4+r, col 16nt+(l&15)
__device__ __forceinline__ void epi(char* dst, uint32_t row0, v4f acc, int nt,
                                    const float* bias){
    uint32_t lane = threadIdx.x & 63u;
    uint32_t col = (uint32_t)nt*16u + (lane & 15u);
    float bv = bias[col];
    uint32_t r0 = row0 + ((lane >> 4) << 2);
    #pragma unroll
    for (int r = 0; r < 4; ++r){
        float v = fmaxf(acc[r] + bv, 0.f);
        *reinterpret_cast<__bf16*>(dst + swz256(r0 + r, col*2u)) = (__bf16)v;
    }
}

// data/leaf GEMM: relu(A @ Wleaf + b), A from bf16 panel, 2 nt per wave
template<int MTN>
__device__ __forceinline__ void gemm_x(const char* xb, uint32_t row0, uint32_t realrows,
                                       char* dst, uint32_t mtB, const v8bf (&wlf)[2][2],
                                       int nt0, const float* bias){
    v4f acc[MTN][2];
    #pragma unroll
    for (int i = 0; i < MTN; ++i){ acc[i][0] = (v4f){0,0,0,0}; acc[i][1] = (v4f){0,0,0,0}; }
    #pragma unroll
    for (uint32_t kf = 0; kf < 2; ++kf){
        v8bf a[MTN];
        #pragma unroll
        for (int i = 0; i < MTN; ++i) a[i] = ldX(xb, row0, mtB + i, kf, realrows);
        #pragma unroll
        for (int i = 0; i < MTN; ++i){
            acc[i][0] = mfma16(a[i], wlf[kf][0], acc[i][0]);
            acc[i][1] = mfma16(a[i], wlf[kf][1], acc[i][1]);
        }
    }
    #pragma unroll
    for (int i = 0; i < MTN; ++i){
        epi(dst, (mtB + i)*16u, acc[i][0], nt0,     bias);
        epi(dst, (mtB + i)*16u, acc[i][1], nt0 + 1, bias);
    }
}

// nl GEMM: relu([h_even|h_odd|u] @ Wnl + b), node-major, 2 nt per wave
template<int MTN>
__device__ __forceinline__ void gemm_nl(const char* hprev, const char* ub, char* dst,
                                        uint32_t mtB, const v8bf (&wnl)[12][2],
                                        int nt0, const float* bias){
    v4f acc[MTN][2];
    #pragma unroll
    for (int i = 0; i < MTN; ++i){ acc[i][0] = (v4f){0,0,0,0}; acc[i][1] = (v4f){0,0,0,0}; }
    #pragma unroll
    for (uint32_t kf = 0; kf < 12; ++kf){
        v8bf a[MTN];
        #pragma unroll
        for (int i = 0; i < MTN; ++i) a[i] = ldA_nl(hprev, ub, mtB + i, kf);
        #pragma unroll
        for (int i = 0; i < MTN; ++i){
            acc[i][0] = mfma16(a[i], wnl[kf][0], acc[i][0]);
            acc[i][1] = mfma16(a[i], wnl[kf][1], acc[i][1]);
        }
    }
    #pragma unroll
    for (int i = 0; i < MTN; ++i){
        epi(dst, (mtB + i)*16u, acc[i][0], nt0,     bias);
        epi(dst, (mtB + i)*16u, acc[i][1], nt0 + 1, bias);
    }
}

__global__ __launch_bounds__(NTHR, 1)
void recnn_kernel(const float* __restrict__ Xg,
                  const float* __restrict__ Wleaf, const float* __restrict__ bleaf,
                  const float* __restrict__ Wnl,   const float* __restrict__ bnl,
                  const float* __restrict__ W1g,   const float* __restrict__ b1g,
                  const float* __restrict__ W2g,   const float* __restrict__ b2g,
                  const float* __restrict__ W3g,   const float* __restrict__ b3g,
                  float* __restrict__ Yg)
{
    __shared__ __align__(16) char lds[LDS_BYTES];
    const int t    = threadIdx.x;
    const int wave = t >> 6;      // 0..3, owns cols [32*wave, 32*wave+32)
    const int base = blockIdx.x * BC;

    char*  XB   = lds + XB_OFF;
    char*  XB2  = lds + XB2_OFF;
    char*  DB   = lds + DB_OFF;
    char*  DB2  = lds + DB2_OFF;
    char*  HA   = lds + HA_OFF;
    char*  HB   = lds + HB_OFF;
    char*  Ub   = lds + U_OFF;
    char*  HCUR = lds + HCUR_OFF;
    char*  DCUR = lds + DCUR_OFF;
    char*  HSTK = lds + HSTK_OFF;
    char*  DSTK = lds + DSTK_OFF;
    float* BL   = (float*)(lds + BIAS_OFF);
    float* BN   = BL + 128;
    float* B1L  = BL + 256;
    float* B2L  = BL + 384;

    if (t < 128){
        BL[t]  = bleaf[t];
        BN[t]  = bnl[t];
        B1L[t] = b1g[t];
        B2L[t] = b2g[t];
    }

    // Persistent weights: 2 nt tiles (32 cols) per wave — 112 VGPRs
    const int nt0 = wave * 2;
    v8bf wlf[2][2], wnl[12][2];
    #pragma unroll
    for (int kf = 0; kf < 2; ++kf){
        wlf[kf][0] = ldW(Wleaf, kf*32, nt0*16);
        wlf[kf][1] = ldW(Wleaf, kf*32, nt0*16 + 16);
    }
    #pragma unroll
    for (int kf = 0; kf < 12; ++kf){
        wnl[kf][0] = ldW(Wnl, kf*32, nt0*16);
        wnl[kf][1] = ldW(Wnl, kf*32, nt0*16 + 16);
    }

    // fused pairwise sum: srcF(swz256,node-major) -> dstF f32 + XB2 bf16 mirror
    auto sum_level = [&](char* dstF, uint32_t dRow0, uint32_t xRow0,
                         const char* srcF, uint32_t sRow0, int outrows){
        int total = outrows * 16;
        for (int idx = t; idx < total; idx += NTHR){
            uint32_t row = (uint32_t)(idx >> 4), q = (uint32_t)(idx & 15);
            uint32_t n = row >> 3, b = row & 7u;
            v4f a = *reinterpret_cast<const v4f*>(srcF + swz256(sRow0 + n*16u + b,      q*16u));
            v4f c = *reinterpret_cast<const v4f*>(srcF + swz256(sRow0 + n*16u + 8u + b, q*16u));
            v4f sv = a + c;
            *reinterpret_cast<v4f*>(dstF + swz256(dRow0 + row, q*16u)) = sv;
            *reinterpret_cast<uint2*>(XB2 + swz128(xRow0 + row, q*8u)) = pk4(sv);
        }
    };

    int sp = 0;
    for (int s = 0; s < NSUB; ++s){
        // push previous root
        if (s > 0){
            #pragma unroll
            for (int k = 0; k < 2; ++k){
                ((uint2*)(HSTK + sp*4096))[t + k*NTHR]    = ((const uint2*)HCUR)[t + k*NTHR];
                ((uint32_t*)(DSTK + sp*2048))[t + k*NTHR] = ((const uint32_t*)DCUR)[t + k*NTHR];
            }
            ++sp;
        }
        // stage: x -> XB bf16; data1 -> DB f32 + XB2[0:64) bf16
        #pragma unroll
        for (int k = 0; k < 4; ++k){
            int idx = t + k*NTHR;                  // 0..1023
            uint32_t rp = (uint32_t)(idx >> 4), q = (uint32_t)(idx & 15);
            uint32_t n = rp >> 3, b = rp & 7u;
            const float* gp = Xg + (size_t)(base + b)*LF + (size_t)(s*16 + 2*n)*FF + q*4;
            v4f xA = *reinterpret_cast<const v4f*>(gp);
            v4f xC = *reinterpret_cast<const v4f*>(gp + FF);
            uint32_t rowA = n*16u + b;
            *reinterpret_cast<uint2*>(XB + swz128(rowA,      q*8u)) = pk4(xA);
            *reinterpret_cast<uint2*>(XB + swz128(rowA + 8u, q*8u)) = pk4(xC);
            v4f sv = xA + xC;
            *reinterpret_cast<v4f*>(DB + swz256(rp, q*16u)) = sv;
            *reinterpret_cast<uint2*>(XB2 + swz128(rp, q*8u)) = pk4(sv);
        }
        __syncthreads();

        // P1: leaf M=128 -> HA ; data2 -> DB2[0:32) + XB2[64:96)
        gemm_x<4>(XB, 0, 128, HA, 0, wlf, nt0, BL);
        gemm_x<4>(XB, 0, 128, HA, 4, wlf, nt0, BL);
        sum_level(DB2, 0, 64, DB, 0, 32);
        __syncthreads();
        // P2: u1 M=64 -> U ; data3 -> DB[0:16) + XB2[96:112)
        gemm_x<4>(XB2, 0, 64, Ub, 0, wlf, nt0, BL);
        sum_level(DB, 0, 96, DB2, 0, 16);
        __syncthreads();
        // P3: nl1 M=64 -> HB ; data4 -> DB2[32:40) + XB2[112:120)
        gemm_nl<4>(HA, Ub, HB, 0, wnl, nt0, BN);
        sum_level(DB2, 32, 112, DB, 0, 8);
        __syncthreads();
        // P4: u2 M=32 -> U
        gemm_x<2>(XB2, 64, 32, Ub, 0, wlf, nt0, BL);
        __syncthreads();
        // P5: nl2 M=32 -> HA[0:32)
        gemm_nl<2>(HB, Ub, HA, 0, wnl, nt0, BN);
        __syncthreads();
        // P6: u3 M=16 -> U
        gemm_x<1>(XB2, 96, 16, Ub, 0, wlf, nt0, BL);
        __syncthreads();
        // P7: nl3 M=16 -> HB[0:16)
        gemm_nl<1>(HA, Ub, HB, 0, wnl, nt0, BN);
        __syncthreads();
        // P8: u4 M=8 -> U
        gemm_x<1>(XB2, 112, 8, Ub, 0, wlf, nt0, BL);
        __syncthreads();
        // P9: nl4 -> HCUR ; copy data4 f32 -> DCUR
        gemm_nl<1>(HB, Ub, HCUR, 0, wnl, nt0, BN);
        #pragma unroll
        for (int k = 0; k < 2; ++k){
            int tt = t + k*NTHR;
            uint32_t row = (uint32_t)(tt >> 6), f = (uint32_t)(tt & 63);
            *reinterpret_cast<float*>(DCUR + swz256(row, f*4u)) =
                *reinterpret_cast<const float*>(DB2 + swz256(32u + row, f*4u));
        }
        __syncthreads();

        // DFS merges among subtree roots (M=8 padded to 16)
        int nm = __builtin_ctz(s + 1);
        for (int m = 0; m < nm; ++m){
            --sp;
            const char* hl = HSTK + sp*4096;
            #pragma unroll
            for (int k = 0; k < 2; ++k){   // root data sum + bf16 mirror -> XB2[120:128)
                int tt = t + k*NTHR;
                uint32_t row = (uint32_t)(tt >> 6), f = (uint32_t)(tt & 63);
                float v = *reinterpret_cast<const float*>(DCUR + swz256(row, f*4u))
                        + *reinterpret_cast<const float*>(DSTK + sp*2048 + swz256(row, f*4u));
                *reinterpret_cast<float*>(DCUR + swz256(row, f*4u)) = v;
                *reinterpret_cast<__bf16*>(XB2 + swz128(120u + row, f*2u)) = (__bf16)v;
            }
            __syncthreads();
            gemm_x<1>(XB2, 120, 8, Ub, 0, wlf, nt0, BL);
            __syncthreads();
            v4f c0 = (v4f){0,0,0,0}, c1 = (v4f){0,0,0,0};
            #pragma unroll
            for (uint32_t kf = 0; kf < 12; ++kf){
                const char* src = (kf < 4) ? hl : ((kf < 8) ? (const char*)HCUR
                                                            : (const char*)Ub);
                v8bf a = ldH(src, kf & 3u);
                c0 = mfma16(a, wnl[kf][0], c0);
                c1 = mfma16(a, wnl[kf][1], c1);
            }
            __syncthreads();   // reads of HCUR done before in-place write
            epi(HCUR, 0, c0, nt0,     BN);
            epi(HCUR, 0, c1, nt0 + 1, BN);
            __syncthreads();
        }
    }

    // ---- head: z1 = relu(enc@W1+b1) -> U; z2 -> HB; out = z2@W3+b3 ----
    {
        v8bf w1f[4][2], w2f[4][2];
        #pragma unroll
        for (int kf = 0; kf < 4; ++kf){
            w1f[kf][0] = ldW(W1g, kf*32, nt0*16);
            w1f[kf][1] = ldW(W1g, kf*32, nt0*16 + 16);
            w2f[kf][0] = ldW(W2g, kf*32, nt0*16);
            w2f[kf][1] = ldW(W2g, kf*32, nt0*16 + 16);
        }
        {
            v4f c0 = (v4f){0,0,0,0}, c1 = (v4f){0,0,0,0};
            #pragma unroll
            for (uint32_t kf = 0; kf < 4; ++kf){
                v8bf a = ldH(HCUR, kf);
                c0 = mfma16(a, w1f[kf][0], c0);
                c1 = mfma16(a, w1f[kf][1], c1);
            }
            epi(Ub, 0, c0, nt0, B1L); epi(Ub, 0, c1, nt0 + 1, B1L);
        }
        __syncthreads();
        {
            v4f c0 = (v4f){0,0,0,0}, c1 = (v4f){0,0,0,0};
            #pragma unroll
            for (uint32_t kf = 0; kf < 4; ++kf){
                v8bf a = ldH(Ub, kf);
                c0 = mfma16(a, w2f[kf][0], c0);
                c1 = mfma16(a, w2f[kf][1], c1);
            }
            epi(HB, 0, c0, nt0, B2L); epi(HB, 0, c1, nt0 + 1, B2L);
        }
        __syncthreads();
        if (t < 64){
            float w3a = W3g[t], w3b = W3g[t + 64], b3v = b3g[0];
            #pragma unroll
            for (int r = 0; r < 8; ++r){
                float za = (float)*reinterpret_cast<const __bf16*>(HB + swz256((uint32_t)r, (uint32_t)t*2u));
                float zb = (float)*reinterpret_cast<const __bf16*>(HB + swz256((uint32_t)r, (uint32_t)(t + 64)*2u));
                float v = za*w3a + zb*w3b;
                #pragma unroll
                for (int off = 32; off >= 1; off >>= 1) v += __shfl_xor(v, off, 64);
                if (t == 0) Yg[base + r] = v + b3v;
            }
        }
    }
}

extern "C" void kernel_launch(void* const* d_in, const int* in_sizes, int n_in,
                              void* d_out, int out_size, void* d_ws, size_t ws_size,
                              hipStream_t stream){
    const float* x     = (const float*)d_in[0];
    const float* Wleaf = (const float*)d_in[1];
    const float* bleaf = (const float*)d_in[2];
    const float* Wnl   = (const float*)d_in[3];
    const float* bnl   = (const float*)d_in[4];
    const float* W1    = (const float*)d_in[5];
    const float* b1    = (const float*)d_in[6];
    const float* W2    = (const float*)d_in[7];
    const float* b2    = (const float*)d_in[8];
    const float* W3    = (const float*)d_in[9];
    const float* b3    = (const float*)d_in[10];
    float* out = (float*)d_out;

    recnn_kernel<<<B_TOT/BC, NTHR, 0, stream>>>(x, Wleaf, bleaf, Wnl, bnl,
                                                W1, b1, W2, b2, W3, b3, out);
}

// Round 10
// 147.925 us; speedup vs baseline: 1.1155x; 1.1155x over previous
//
#include <hip/hip_runtime.h>
#include <hip/hip_bf16.h>
#include <stdint.h>

// RecNN: B=2048, L=256, F=64, H=128. One WG (512 thr, 8 waves) per 8 batch
// elems. Subtree-BFS(16 leaves) + DFS over 16 roots. Each wave owns ONE
// 16-col output tile (nt=wave, 56 weight VGPRs): the proven no-spill config
// at 2 waves/SIMD (round 8, 129us). Round 9 showed 32-col/wave @ 1 wave/SIMD
// is latency-bound (165us) — 2 waves/SIMD is mandatory, so 16 cols it is.
// Round 10 deltas vs round 8 (math identical):
//  - epi pairs lanes via shfl_xor(1): 2 aligned u32 LDS writes instead of 4
//    scalar bf16 writes (same-dword write conflicts were ~55k cyc/CU).
//  - phase fusion: {nl_i, u_{i+1}} share a phase; 10 -> 7 barriers/subtree.
//    u2 lives in the dead data2-f32 region (U2 = DB2 rows 0-31).
//  - merge loop: HCUR double-buffered -> 2 barriers/merge instead of 4.
//  - HSTK slots store only the 8 real rows; pad-row overreads are benign
//    (NaN * W -> pad rows only; epi's fmaxf(NaN,0)=0 keeps pads finite).

#define B_TOT 2048
#define LL    256
#define FF    64
#define HH    128
#define LF    (LL*FF)
#define BC    8
#define NTHR  512
#define NSUB  16

typedef __bf16 v8bf __attribute__((ext_vector_type(8)));
typedef float  v4f  __attribute__((ext_vector_type(4)));

// ---- LDS layout (bytes) ----
#define XB_OFF    0        // [128]x128B bf16 swz128: leaf x            16384
#define XB2_OFF   16384    // [128]x128B bf16 swz128: data1..4 + root   16384
#define DB_OFF    32768    // [64]x256B f32 swz256: data1 / data3       16384
#define DB2_OFF   49152    // [40]x256B: rows0-31 data2 f32 then U2 bf16;
                           //            rows32-39 data4 f32            10240
#define HA_OFF    59392    // [128]x256B bf16 swz256: h0 / h2           32768
#define HB_OFF    92160    // [64]x256B bf16: h1 / h3 / z2              16384
#define U_OFF     108544   // [64]x256B bf16: u1 / u3@0 / u4@16 / z1    16384
#define HCA_OFF   124928   // [16]x256B bf16: root h (buffer A)          4096
#define HCB_OFF   129024   // [16]x256B bf16: root h (buffer B)          4096
#define DCUR_OFF  133120   // [8]x256B f32: root data                    2048
#define HSTK_OFF  135168   // 4 x 2048 (8 real rows each)                8192
#define DSTK_OFF  143360   // 4 x 2048                                   8192
#define BIAS_OFF  151552   // 4 x 512B f32                               2048
#define LDS_BYTES 153600

__device__ __forceinline__ uint32_t swz256(uint32_t row, uint32_t b){
    return (row*256u + b) ^ ((row & 7u) << 4);
}
__device__ __forceinline__ uint32_t swz128(uint32_t row, uint32_t b){
    return (row*128u + b) ^ ((row & 7u) << 4);
}
__device__ __forceinline__ v4f mfma16(v8bf a, v8bf b, v4f c){
    return __builtin_amdgcn_mfma_f32_16x16x32_bf16(a, b, c, 0, 0, 0);
}
__device__ __forceinline__ uint32_t pk2(float a, float b){
    uint32_t lo = (uint32_t)__builtin_bit_cast(unsigned short, (__bf16)a);
    uint32_t hi = (uint32_t)__builtin_bit_cast(unsigned short, (__bf16)b);
    return lo | (hi << 16);
}
__device__ __forceinline__ uint2 pk4(v4f v){
    return make_uint2(pk2(v[0], v[1]), pk2(v[2], v[3]));
}

// B-fragment: lane holds col n0+(l&15), k = k0 + 8*(l>>4) + j. W row-major [K][128] f32.
__device__ __forceinline__ v8bf ldW(const float* __restrict__ W, int k0, int n0){
    uint32_t lane = threadIdx.x & 63u;
    int n = n0 + (int)(lane & 15u);
    int k = k0 + (int)((lane >> 4) << 3);
    v8bf r;
    #pragma unroll
    for (int j = 0; j < 8; ++j) r[j] = (__bf16)W[(k + j)*HH + n];
    return r;
}

// A-frag from bf16 64-col panel (swz128). rows >= realrows -> 0.
__device__ __forceinline__ v8bf ldX(const char* xb, uint32_t row0, uint32_t mt,
                                    uint32_t kf, uint32_t realrows){
    uint32_t lane = threadIdx.x & 63u;
    uint32_t rl = mt*16u + (lane & 15u);
    if (rl >= realrows){
        v8bf z;
        #pragma unroll
        for (int j = 0; j < 8; ++j) z[j] = (__bf16)0.0f;
        return z;
    }
    return *reinterpret_cast<const v8bf*>(xb + swz128(row0 + rl, kf*64u + ((lane>>4)<<4)));
}

// A-frag from 16-row bf16 buffer (swz256), row = lane&15 (merge/head GEMMs)
__device__ __forceinline__ v8bf ldH(const char* buf, uint32_t kf){
    uint32_t lane = threadIdx.x & 63u;
    return *reinterpret_cast<const v8bf*>(buf + swz256(lane & 15u,
                                          kf*64u + ((lane>>4)<<4)));
}

// A-frag for subtree nl GEMM (node-major): out tile mt -> nodes 2mt,2mt+1;
// children rows 32mt+16*(r>=8)+8*sec+(r&7); u row 16mt+r.
__device__ __forceinline__ v8bf ldA_nl(const char* hprev, const char* ub,
                                       uint32_t mt, uint32_t kf){
    uint32_t lane = threadIdx.x & 63u, r = lane & 15u;
    uint32_t kb = (kf & 3u)*64u + ((lane >> 4) << 4);
    uint32_t sec = kf >> 2;
    if (sec < 2u){
        uint32_t row = mt*32u + ((r >> 3) << 4) + sec*8u + (r & 7u);
        return *reinterpret_cast<const v8bf*>(hprev + swz256(row, kb));
    }
    return *reinterpret_cast<const v8bf*>(ub + swz256(mt*16u + r, kb));
}

// Epilogue: relu(acc+bias) -> bf16 swz256 LDS. Lane pair (l, l^1) exchanges
// values via shfl_xor (DPP) so each lane emits 2 aligned u32 writes instead
// of 4 scalar bf16 writes (same-dword write conflicts eliminated).
__device__ __forceinline__ void epi(char* dst, uint32_t row0, v4f acc, int nt,
                                    const float* bias){
    uint32_t lane = threadIdx.x & 63u;
    uint32_t col = (uint32_t)nt*16u + (lane & 15u);
    float bv = bias[col];
    float v0 = fmaxf(acc[0] + bv, 0.f);
    float v1 = fmaxf(acc[1] + bv, 0.f);
    float v2 = fmaxf(acc[2] + bv, 0.f);
    float v3 = fmaxf(acc[3] + bv, 0.f);
    float p0 = __shfl_xor(v0, 1);
    float p1 = __shfl_xor(v1, 1);
    float p2 = __shfl_xor(v2, 1);
    float p3 = __shfl_xor(v3, 1);
    uint32_t r0 = row0 + ((lane >> 4) << 2);
    bool odd = (lane & 1u);
    uint32_t w0 = odd ? pk2(p2, v2) : pk2(v0, p0);
    uint32_t w1 = odd ? pk2(p3, v3) : pk2(v1, p1);
    uint32_t r  = odd ? (r0 + 2u) : r0;
    uint32_t cb = (col & ~1u) * 2u;
    *reinterpret_cast<uint32_t*>(dst + swz256(r,      cb)) = w0;
    *reinterpret_cast<uint32_t*>(dst + swz256(r + 1u, cb)) = w1;
}

// data/leaf GEMM: relu(A @ Wleaf + b), A from bf16 panel, 1 nt per wave
template<int MTN>
__device__ __forceinline__ void gemm_x(const char* xb, uint32_t row0, uint32_t realrows,
                                       char* dst, uint32_t mtB, const v8bf (&wlf)[2],
                                       int nt, const float* bias){
    v4f acc[MTN];
    #pragma unroll
    for (int i = 0; i < MTN; ++i) acc[i] = (v4f){0,0,0,0};
    #pragma unroll
    for (uint32_t kf = 0; kf < 2; ++kf){
        v8bf a[MTN];
        #pragma unroll
        for (int i = 0; i < MTN; ++i) a[i] = ldX(xb, row0, mtB + i, kf, realrows);
        #pragma unroll
        for (int i = 0; i < MTN; ++i) acc[i] = mfma16(a[i], wlf[kf], acc[i]);
    }
    #pragma unroll
    for (int i = 0; i < MTN; ++i) epi(dst, (mtB + i)*16u, acc[i], nt, bias);
}

// nl GEMM: relu([h_even|h_odd|u] @ Wnl + b), node-major, 1 nt per wave
template<int MTN>
__device__ __forceinline__ void gemm_nl(const char* hprev, const char* ub, char* dst,
                                        uint32_t mtB, const v8bf (&wnl)[12],
                                        int nt, const float* bias){
    v4f acc[MTN];
    #pragma unroll
    for (int i = 0; i < MTN; ++i) acc[i] = (v4f){0,0,0,0};
    #pragma unroll
    for (uint32_t kf = 0; kf < 12; ++kf){
        v8bf a[MTN];
        #pragma unroll
        for (int i = 0; i < MTN; ++i) a[i] = ldA_nl(hprev, ub, mtB + i, kf);
        #pragma unroll
        for (int i = 0; i < MTN; ++i) acc[i] = mfma16(a[i], wnl[kf], acc[i]);
    }
    #pragma unroll
    for (int i = 0; i < MTN; ++i) epi(dst, (mtB + i)*16u, acc[i], nt, bias);
}

__global__ __launch_bounds__(NTHR)
__attribute__((amdgpu_waves_per_eu(2, 2)))
void recnn_kernel(const float* __restrict__ Xg,
                  const float* __restrict__ Wleaf, const float* __restrict__ bleaf,
                  const float* __restrict__ Wnl,   const float* __restrict__ bnl,
                  const float* __restrict__ W1g,   const float* __restrict__ b1g,
                  const float* __restrict__ W2g,   const float* __restrict__ b2g,
                  const float* __restrict__ W3g,   const float* __restrict__ b3g,
                  float* __restrict__ Yg)
{
    __shared__ __align__(16) char lds[LDS_BYTES];
    const int t    = threadIdx.x;
    const int wave = t >> 6;
    const int base = blockIdx.x * BC;

    char*  XB   = lds + XB_OFF;
    char*  XB2  = lds + XB2_OFF;
    char*  DB   = lds + DB_OFF;
    char*  DB2  = lds + DB2_OFF;
    char*  U2   = lds + DB2_OFF;           // rows 0-31, bf16 (data2-f32 is dead by then)
    char*  HA   = lds + HA_OFF;
    char*  HB   = lds + HB_OFF;
    char*  Ub   = lds + U_OFF;
    char*  DCUR = lds + DCUR_OFF;
    char*  HSTK = lds + HSTK_OFF;
    char*  DSTK = lds + DSTK_OFF;
    float* BL   = (float*)(lds + BIAS_OFF);
    float* BN   = BL + 128;
    float* B1L  = BL + 256;
    float* B2L  = BL + 384;

    char* hc_cur = lds + HCA_OFF;
    char* hc_alt = lds + HCB_OFF;

    if (t < 128){
        BL[t]  = bleaf[t];
        BN[t]  = bnl[t];
        B1L[t] = b1g[t];
        B2L[t] = b2g[t];
    }

    // Persistent weights: wave owns output cols [16*wave, 16*wave+16) — 56 VGPRs
    const int nt = wave;
    const int n0 = wave << 4;
    v8bf wlf[2], wnl[12];
    #pragma unroll
    for (int kf = 0; kf < 2; ++kf)  wlf[kf] = ldW(Wleaf, kf*32, n0);
    #pragma unroll
    for (int kf = 0; kf < 12; ++kf) wnl[kf] = ldW(Wnl, kf*32, n0);

    // fused pairwise sum: srcF(swz256,node-major) -> dstF f32 + XB2 bf16 mirror
    auto sum_level = [&](char* dstF, uint32_t dRow0, uint32_t xRow0,
                         const char* srcF, uint32_t sRow0, int outrows){
        int total = outrows * 16;
        for (int idx = t; idx < total; idx += NTHR){
            uint32_t row = (uint32_t)(idx >> 4), q = (uint32_t)(idx & 15);
            uint32_t n = row >> 3, b = row & 7u;
            v4f a = *reinterpret_cast<const v4f*>(srcF + swz256(sRow0 + n*16u + b,      q*16u));
            v4f c = *reinterpret_cast<const v4f*>(srcF + swz256(sRow0 + n*16u + 8u + b, q*16u));
            v4f sv = a + c;
            *reinterpret_cast<v4f*>(dstF + swz256(dRow0 + row, q*16u)) = sv;
            *reinterpret_cast<uint2*>(XB2 + swz128(xRow0 + row, q*8u)) = pk4(sv);
        }
    };

    int sp = 0;
    for (int s = 0; s < NSUB; ++s){
        // push previous root (8 real rows = 2048B each; pad-row overreads benign)
        if (s > 0){
            ((uint32_t*)(HSTK + sp*2048))[t] = ((const uint32_t*)hc_cur)[t];
            ((uint32_t*)(DSTK + sp*2048))[t] = ((const uint32_t*)DCUR)[t];
            ++sp;
        }
        // stage: x -> XB bf16; data1 -> DB f32 + XB2[0:64) bf16
        #pragma unroll
        for (int k = 0; k < 2; ++k){
            int idx = t + k*NTHR;                  // 0..1023
            uint32_t rp = (uint32_t)(idx >> 4), q = (uint32_t)(idx & 15);
            uint32_t n = rp >> 3, b = rp & 7u;
            const float* gp = Xg + (size_t)(base + b)*LF + (size_t)(s*16 + 2*n)*FF + q*4;
            v4f xA = *reinterpret_cast<const v4f*>(gp);
            v4f xC = *reinterpret_cast<const v4f*>(gp + FF);
            uint32_t rowA = n*16u + b;
            *reinterpret_cast<uint2*>(XB + swz128(rowA,      q*8u)) = pk4(xA);
            *reinterpret_cast<uint2*>(XB + swz128(rowA + 8u, q*8u)) = pk4(xC);
            v4f sv = xA + xC;
            *reinterpret_cast<v4f*>(DB + swz256(rp, q*16u)) = sv;
            *reinterpret_cast<uint2*>(XB2 + swz128(rp, q*8u)) = pk4(sv);
        }
        __syncthreads();

        // F1: leaf M=128 -> HA ; data2 = sum(data1) -> DB2[0:32)f32 + XB2[64:96)
        gemm_x<4>(XB, 0, 128, HA, 0, wlf, nt, BL);
        gemm_x<4>(XB, 0, 128, HA, 4, wlf, nt, BL);
        sum_level(DB2, 0, 64, DB, 0, 32);
        __syncthreads();

        // F2: u1 M=64 -> U ; data3 = sum(data2 f32) -> DB[0:16) + XB2[96:112)
        gemm_x<4>(XB2, 0, 64, Ub, 0, wlf, nt, BL);
        sum_level(DB, 0, 96, DB2, 0, 16);
        __syncthreads();

        // F3: nl1 M=64 -> HB ; u2 M=32 -> U2 (over dead data2 f32) ;
        //     data4 = sum(data3) -> DB2[32:40) + XB2[112:120)
        gemm_nl<4>(HA, Ub, HB, 0, wnl, nt, BN);
        gemm_x<2>(XB2, 64, 32, U2, 0, wlf, nt, BL);
        sum_level(DB2, 32, 112, DB, 0, 8);
        __syncthreads();

        // F4: nl2 M=32 -> HA[0:32) ; u3 M=16 -> U[0:16)
        gemm_nl<2>(HB, U2, HA, 0, wnl, nt, BN);
        gemm_x<1>(XB2, 96, 16, Ub, 0, wlf, nt, BL);
        __syncthreads();

        // F5: nl3 M=16 -> HB[0:16) ; u4 M=8 -> U[16:32)
        gemm_nl<1>(HA, Ub, HB, 0, wnl, nt, BN);
        gemm_x<1>(XB2, 112, 8, Ub + 16*256, 0, wlf, nt, BL);
        __syncthreads();

        // F6: nl4 -> hc_cur ; DCUR <- data4 f32
        gemm_nl<1>(HB, Ub + 16*256, hc_cur, 0, wnl, nt, BN);
        {
            uint32_t row = (uint32_t)(t >> 6), f = (uint32_t)(t & 63);
            *reinterpret_cast<float*>(DCUR + swz256(row, f*4u)) =
                *reinterpret_cast<const float*>(DB2 + swz256(32u + row, f*4u));
        }
        __syncthreads();

        // DFS merges among subtree roots (M=8 padded to 16), HCUR double-buffered
        int nm = __builtin_ctz(s + 1);
        for (int m = 0; m < nm; ++m){
            --sp;
            const char* hl = HSTK + sp*2048;
            {   // (a) root data sum + bf16 mirror -> XB2[120:128)
                uint32_t row = (uint32_t)(t >> 6), f = (uint32_t)(t & 63);
                float v = *reinterpret_cast<const float*>(DCUR + swz256(row, f*4u))
                        + *reinterpret_cast<const float*>(DSTK + sp*2048 + swz256(row, f*4u));
                *reinterpret_cast<float*>(DCUR + swz256(row, f*4u)) = v;
                *reinterpret_cast<__bf16*>(XB2 + swz128(120u + row, f*2u)) = (__bf16)v;
            }
            __syncthreads();
            // (b) u-merge M=8 -> U[0:16)
            gemm_x<1>(XB2, 120, 8, Ub, 0, wlf, nt, BL);
            __syncthreads();
            // (c) nl-merge -> hc_alt (no in-place hazard; no barrier except last)
            v4f c = (v4f){0,0,0,0};
            #pragma unroll
            for (uint32_t kf = 0; kf < 12; ++kf){
                const char* src = (kf < 4) ? hl : ((kf < 8) ? (const char*)hc_cur
                                                            : (const char*)Ub);
                c = mfma16(ldH(src, kf & 3u), wnl[kf], c);
            }
            epi(hc_alt, 0, c, nt, BN);
            { char* tmp = hc_cur; hc_cur = hc_alt; hc_alt = tmp; }
            if (m == nm - 1) __syncthreads();
        }
    }

    // ---- head: z1 = relu(root@W1+b1) -> U; z2 -> HB; out = z2@W3+b3 ----
    {
        v8bf w1f[4], w2f[4];
        #pragma unroll
        for (int kf = 0; kf < 4; ++kf){
            w1f[kf] = ldW(W1g, kf*32, n0);
            w2f[kf] = ldW(W2g, kf*32, n0);
        }
        {
            v4f c = (v4f){0,0,0,0};
            #pragma unroll
            for (uint32_t kf = 0; kf < 4; ++kf) c = mfma16(ldH(hc_cur, kf), w1f[kf], c);
            epi(Ub, 0, c, nt, B1L);
        }
        __syncthreads();
        {
            v4f c = (v4f){0,0,0,0};
            #pragma unroll
            for (uint32_t kf = 0; kf < 4; ++kf) c = mfma16(ldH(Ub, kf), w2f[kf], c);
            epi(HB, 0, c, nt, B2L);
        }
        __syncthreads();
        if (t < 64){
            float w3a = W3g[t], w3b = W3g[t + 64], b3v = b3g[0];
            #pragma unroll
            for (int r = 0; r < 8; ++r){
                float za = (float)*reinterpret_cast<const __bf16*>(HB + swz256((uint32_t)r, (uint32_t)t*2u));
                float zb = (float)*reinterpret_cast<const __bf16*>(HB + swz256((uint32_t)r, (uint32_t)(t + 64)*2u));
                float v = za*w3a + zb*w3b;
                #pragma unroll
                for (int off = 32; off >= 1; off >>= 1) v += __shfl_xor(v, off, 64);
                if (t == 0) Yg[base + r] = v + b3v;
            }
        }
    }
}

extern "C" void kernel_launch(void* const* d_in, const int* in_sizes, int n_in,
                              void* d_out, int out_size, void* d_ws, size_t ws_size,
                              hipStream_t stream){
    const float* x     = (const float*)d_in[0];
    const float* Wleaf = (const float*)d_in[1];
    const float* bleaf = (const float*)d_in[2];
    const float* Wnl   = (const float*)d_in[3];
    const float* bnl   = (const float*)d_in[4];
    const float* W1    = (const float*)d_in[5];
    const float* b1    = (const float*)d_in[6];
    const float* W2    = (const float*)d_in[7];
    const float* b2    = (const float*)d_in[8];
    const float* W3    = (const float*)d_in[9];
    const float* b3    = (const float*)d_in[10];
    float* out = (float*)d_out;

    recnn_kernel<<<B_TOT/BC, NTHR, 0, stream>>>(x, Wleaf, bleaf, Wnl, bnl,
                                                W1, b1, W2, b2, W3, b3, out);
}

// Round 11
// 125.685 us; speedup vs baseline: 1.3129x; 1.1770x over previous
//
#include <hip/hip_runtime.h>
#include <hip/hip_bf16.h>
#include <stdint.h>

// RecNN: B=2048, L=256, F=64, H=128. One WG (512 thr, 8 waves) per 8 batch
// elems. Subtree-BFS(16 leaves) + DFS over 16 roots. Each wave owns ONE
// 16-col output tile (nt=wave, 56 weight VGPRs) — proven no-spill config at
// 2 waves/SIMD (round 8, 129us; 2-wave/SIMD occupancy is mandatory, round 9).
// Round 11 = round 8 + BARRIER-FUSION ONLY (round-10 ablation: its epi
// shuffle rewrite added VALU cost with zero conflict benefit — conflicts are
// read-side; epi reverted to round-8 scalar writes):
//  - phase fusion: {nl_i, u_{i+1}} share a phase; ~10 -> 7 barriers/subtree.
//    u2 lives in the dead data2-f32 region (U2 = DB2 rows 0-31).
//  - merge loop: HCUR double-buffered -> 2 barriers/merge instead of 4.
//  - HSTK slots store only the 8 real rows; pad-row overreads are benign.

#define B_TOT 2048
#define LL    256
#define FF    64
#define HH    128
#define LF    (LL*FF)
#define BC    8
#define NTHR  512
#define NSUB  16

typedef __bf16 v8bf __attribute__((ext_vector_type(8)));
typedef float  v4f  __attribute__((ext_vector_type(4)));

// ---- LDS layout (bytes) ----
#define XB_OFF    0        // [128]x128B bf16 swz128: leaf x            16384
#define XB2_OFF   16384    // [128]x128B bf16 swz128: data1..4 + root   16384
#define DB_OFF    32768    // [64]x256B f32 swz256: data1 / data3       16384
#define DB2_OFF   49152    // [40]x256B: rows0-31 data2 f32 then U2 bf16;
                           //            rows32-39 data4 f32            10240
#define HA_OFF    59392    // [128]x256B bf16 swz256: h0 / h2           32768
#define HB_OFF    92160    // [64]x256B bf16: h1 / h3 / z2              16384
#define U_OFF     108544   // [64]x256B bf16: u1 / u3@0 / u4@16 / z1    16384
#define HCA_OFF   124928   // [16]x256B bf16: root h (buffer A)          4096
#define HCB_OFF   129024   // [16]x256B bf16: root h (buffer B)          4096
#define DCUR_OFF  133120   // [8]x256B f32: root data                    2048
#define HSTK_OFF  135168   // 4 x 2048 (8 real rows each)                8192
#define DSTK_OFF  143360   // 4 x 2048                                   8192
#define BIAS_OFF  151552   // 4 x 512B f32                               2048
#define LDS_BYTES 153600

__device__ __forceinline__ uint32_t swz256(uint32_t row, uint32_t b){
    return (row*256u + b) ^ ((row & 7u) << 4);
}
__device__ __forceinline__ uint32_t swz128(uint32_t row, uint32_t b){
    return (row*128u + b) ^ ((row & 7u) << 4);
}
__device__ __forceinline__ v4f mfma16(v8bf a, v8bf b, v4f c){
    return __builtin_amdgcn_mfma_f32_16x16x32_bf16(a, b, c, 0, 0, 0);
}
__device__ __forceinline__ uint32_t pk2(float a, float b){
    uint32_t lo = (uint32_t)__builtin_bit_cast(unsigned short, (__bf16)a);
    uint32_t hi = (uint32_t)__builtin_bit_cast(unsigned short, (__bf16)b);
    return lo | (hi << 16);
}
__device__ __forceinline__ uint2 pk4(v4f v){
    return make_uint2(pk2(v[0], v[1]), pk2(v[2], v[3]));
}

// B-fragment: lane holds col n0+(l&15), k = k0 + 8*(l>>4) + j. W row-major [K][128] f32.
__device__ __forceinline__ v8bf ldW(const float* __restrict__ W, int k0, int n0){
    uint32_t lane = threadIdx.x & 63u;
    int n = n0 + (int)(lane & 15u);
    int k = k0 + (int)((lane >> 4) << 3);
    v8bf r;
    #pragma unroll
    for (int j = 0; j < 8; ++j) r[j] = (__bf16)W[(k + j)*HH + n];
    return r;
}

// A-frag from bf16 64-col panel (swz128). rows >= realrows -> 0.
__device__ __forceinline__ v8bf ldX(const char* xb, uint32_t row0, uint32_t mt,
                                    uint32_t kf, uint32_t realrows){
    uint32_t lane = threadIdx.x & 63u;
    uint32_t rl = mt*16u + (lane & 15u);
    if (rl >= realrows){
        v8bf z;
        #pragma unroll
        for (int j = 0; j < 8; ++j) z[j] = (__bf16)0.0f;
        return z;
    }
    return *reinterpret_cast<const v8bf*>(xb + swz128(row0 + rl, kf*64u + ((lane>>4)<<4)));
}

// A-frag from 16-row bf16 buffer (swz256), row = lane&15 (merge/head GEMMs)
__device__ __forceinline__ v8bf ldH(const char* buf, uint32_t kf){
    uint32_t lane = threadIdx.x & 63u;
    return *reinterpret_cast<const v8bf*>(buf + swz256(lane & 15u,
                                          kf*64u + ((lane>>4)<<4)));
}

// A-frag for subtree nl GEMM (node-major): out tile mt -> nodes 2mt,2mt+1;
// children rows 32mt+16*(r>=8)+8*sec+(r&7); u row 16mt+r.
__device__ __forceinline__ v8bf ldA_nl(const char* hprev, const char* ub,
                                       uint32_t mt, uint32_t kf){
    uint32_t lane = threadIdx.x & 63u, r = lane & 15u;
    uint32_t kb = (kf & 3u)*64u + ((lane >> 4) << 4);
    uint32_t sec = kf >> 2;
    if (sec < 2u){
        uint32_t row = mt*32u + ((r >> 3) << 4) + sec*8u + (r & 7u);
        return *reinterpret_cast<const v8bf*>(hprev + swz256(row, kb));
    }
    return *reinterpret_cast<const v8bf*>(ub + swz256(mt*16u + r, kb));
}

// Epilogue (round-8 version): relu(acc+bias) -> bf16 swz256 LDS,
// rows row0+(l>>4)*4+r, col 16nt+(l&15).
__device__ __forceinline__ void epi(char* dst, uint32_t row0, v4f acc, int nt,
                                    const float* bias){
    uint32_t lane = threadIdx.x & 63u;
    uint32_t col = (uint32_t)nt*16u + (lane & 15u);
    float bv = bias[col];
    uint32_t r0 = row0 + ((lane >> 4) << 2);
    #pragma unroll
    for (int r = 0; r < 4; ++r){
        float v = fmaxf(acc[r] + bv, 0.f);
        *reinterpret_cast<__bf16*>(dst + swz256(r0 + r, col*2u)) = (__bf16)v;
    }
}

// data/leaf GEMM: relu(A @ Wleaf + b), A from bf16 panel, 1 nt per wave
template<int MTN>
__device__ __forceinline__ void gemm_x(const char* xb, uint32_t row0, uint32_t realrows,
                                       char* dst, uint32_t mtB, const v8bf (&wlf)[2],
                                       int nt, const float* bias){
    v4f acc[MTN];
    #pragma unroll
    for (int i = 0; i < MTN; ++i) acc[i] = (v4f){0,0,0,0};
    #pragma unroll
    for (uint32_t kf = 0; kf < 2; ++kf){
        v8bf a[MTN];
        #pragma unroll
        for (int i = 0; i < MTN; ++i) a[i] = ldX(xb, row0, mtB + i, kf, realrows);
        #pragma unroll
        for (int i = 0; i < MTN; ++i) acc[i] = mfma16(a[i], wlf[kf], acc[i]);
    }
    #pragma unroll
    for (int i = 0; i < MTN; ++i) epi(dst, (mtB + i)*16u, acc[i], nt, bias);
}

// nl GEMM: relu([h_even|h_odd|u] @ Wnl + b), node-major, 1 nt per wave
template<int MTN>
__device__ __forceinline__ void gemm_nl(const char* hprev, const char* ub, char* dst,
                                        uint32_t mtB, const v8bf (&wnl)[12],
                                        int nt, const float* bias){
    v4f acc[MTN];
    #pragma unroll
    for (int i = 0; i < MTN; ++i) acc[i] = (v4f){0,0,0,0};
    #pragma unroll
    for (uint32_t kf = 0; kf < 12; ++kf){
        v8bf a[MTN];
        #pragma unroll
        for (int i = 0; i < MTN; ++i) a[i] = ldA_nl(hprev, ub, mtB + i, kf);
        #pragma unroll
        for (int i = 0; i < MTN; ++i) acc[i] = mfma16(a[i], wnl[kf], acc[i]);
    }
    #pragma unroll
    for (int i = 0; i < MTN; ++i) epi(dst, (mtB + i)*16u, acc[i], nt, bias);
}

__global__ __launch_bounds__(NTHR)
__attribute__((amdgpu_waves_per_eu(2, 2)))
void recnn_kernel(const float* __restrict__ Xg,
                  const float* __restrict__ Wleaf, const float* __restrict__ bleaf,
                  const float* __restrict__ Wnl,   const float* __restrict__ bnl,
                  const float* __restrict__ W1g,   const float* __restrict__ b1g,
                  const float* __restrict__ W2g,   const float* __restrict__ b2g,
                  const float* __restrict__ W3g,   const float* __restrict__ b3g,
                  float* __restrict__ Yg)
{
    __shared__ __align__(16) char lds[LDS_BYTES];
    const int t    = threadIdx.x;
    const int wave = t >> 6;
    const int base = blockIdx.x * BC;

    char*  XB   = lds + XB_OFF;
    char*  XB2  = lds + XB2_OFF;
    char*  DB   = lds + DB_OFF;
    char*  DB2  = lds + DB2_OFF;
    char*  U2   = lds + DB2_OFF;           // rows 0-31, bf16 (data2-f32 dead by then)
    char*  HA   = lds + HA_OFF;
    char*  HB   = lds + HB_OFF;
    char*  Ub   = lds + U_OFF;
    char*  DCUR = lds + DCUR_OFF;
    char*  HSTK = lds + HSTK_OFF;
    char*  DSTK = lds + DSTK_OFF;
    float* BL   = (float*)(lds + BIAS_OFF);
    float* BN   = BL + 128;
    float* B1L  = BL + 256;
    float* B2L  = BL + 384;

    char* hc_cur = lds + HCA_OFF;
    char* hc_alt = lds + HCB_OFF;

    if (t < 128){
        BL[t]  = bleaf[t];
        BN[t]  = bnl[t];
        B1L[t] = b1g[t];
        B2L[t] = b2g[t];
    }

    // Persistent weights: wave owns output cols [16*wave, 16*wave+16) — 56 VGPRs
    const int nt = wave;
    const int n0 = wave << 4;
    v8bf wlf[2], wnl[12];
    #pragma unroll
    for (int kf = 0; kf < 2; ++kf)  wlf[kf] = ldW(Wleaf, kf*32, n0);
    #pragma unroll
    for (int kf = 0; kf < 12; ++kf) wnl[kf] = ldW(Wnl, kf*32, n0);

    // fused pairwise sum: srcF(swz256,node-major) -> dstF f32 + XB2 bf16 mirror
    auto sum_level = [&](char* dstF, uint32_t dRow0, uint32_t xRow0,
                         const char* srcF, uint32_t sRow0, int outrows){
        int total = outrows * 16;
        for (int idx = t; idx < total; idx += NTHR){
            uint32_t row = (uint32_t)(idx >> 4), q = (uint32_t)(idx & 15);
            uint32_t n = row >> 3, b = row & 7u;
            v4f a = *reinterpret_cast<const v4f*>(srcF + swz256(sRow0 + n*16u + b,      q*16u));
            v4f c = *reinterpret_cast<const v4f*>(srcF + swz256(sRow0 + n*16u + 8u + b, q*16u));
            v4f sv = a + c;
            *reinterpret_cast<v4f*>(dstF + swz256(dRow0 + row, q*16u)) = sv;
            *reinterpret_cast<uint2*>(XB2 + swz128(xRow0 + row, q*8u)) = pk4(sv);
        }
    };

    int sp = 0;
    for (int s = 0; s < NSUB; ++s){
        // push previous root (8 real rows = 2048B each)
        if (s > 0){
            ((uint32_t*)(HSTK + sp*2048))[t] = ((const uint32_t*)hc_cur)[t];
            ((uint32_t*)(DSTK + sp*2048))[t] = ((const uint32_t*)DCUR)[t];
            ++sp;
        }
        // stage: x -> XB bf16; data1 -> DB f32 + XB2[0:64) bf16
        #pragma unroll
        for (int k = 0; k < 2; ++k){
            int idx = t + k*NTHR;                  // 0..1023
            uint32_t rp = (uint32_t)(idx >> 4), q = (uint32_t)(idx & 15);
            uint32_t n = rp >> 3, b = rp & 7u;
            const float* gp = Xg + (size_t)(base + b)*LF + (size_t)(s*16 + 2*n)*FF + q*4;
            v4f xA = *reinterpret_cast<const v4f*>(gp);
            v4f xC = *reinterpret_cast<const v4f*>(gp + FF);
            uint32_t rowA = n*16u + b;
            *reinterpret_cast<uint2*>(XB + swz128(rowA,      q*8u)) = pk4(xA);
            *reinterpret_cast<uint2*>(XB + swz128(rowA + 8u, q*8u)) = pk4(xC);
            v4f sv = xA + xC;
            *reinterpret_cast<v4f*>(DB + swz256(rp, q*16u)) = sv;
            *reinterpret_cast<uint2*>(XB2 + swz128(rp, q*8u)) = pk4(sv);
        }
        __syncthreads();

        // F1: leaf M=128 -> HA ; data2 = sum(data1) -> DB2[0:32)f32 + XB2[64:96)
        gemm_x<4>(XB, 0, 128, HA, 0, wlf, nt, BL);
        gemm_x<4>(XB, 0, 128, HA, 4, wlf, nt, BL);
        sum_level(DB2, 0, 64, DB, 0, 32);
        __syncthreads();

        // F2: u1 M=64 -> U ; data3 = sum(data2 f32) -> DB[0:16) + XB2[96:112)
        gemm_x<4>(XB2, 0, 64, Ub, 0, wlf, nt, BL);
        sum_level(DB, 0, 96, DB2, 0, 16);
        __syncthreads();

        // F3: nl1 M=64 -> HB ; u2 M=32 -> U2 (over dead data2 f32) ;
        //     data4 = sum(data3) -> DB2[32:40) + XB2[112:120)
        gemm_nl<4>(HA, Ub, HB, 0, wnl, nt, BN);
        gemm_x<2>(XB2, 64, 32, U2, 0, wlf, nt, BL);
        sum_level(DB2, 32, 112, DB, 0, 8);
        __syncthreads();

        // F4: nl2 M=32 -> HA[0:32) ; u3 M=16 -> U[0:16)
        gemm_nl<2>(HB, U2, HA, 0, wnl, nt, BN);
        gemm_x<1>(XB2, 96, 16, Ub, 0, wlf, nt, BL);
        __syncthreads();

        // F5: nl3 M=16 -> HB[0:16) ; u4 M=8 -> U[16:32)
        gemm_nl<1>(HA, Ub, HB, 0, wnl, nt, BN);
        gemm_x<1>(XB2, 112, 8, Ub + 16*256, 0, wlf, nt, BL);
        __syncthreads();

        // F6: nl4 -> hc_cur ; DCUR <- data4 f32
        gemm_nl<1>(HB, Ub + 16*256, hc_cur, 0, wnl, nt, BN);
        {
            uint32_t row = (uint32_t)(t >> 6), f = (uint32_t)(t & 63);
            *reinterpret_cast<float*>(DCUR + swz256(row, f*4u)) =
                *reinterpret_cast<const float*>(DB2 + swz256(32u + row, f*4u));
        }
        __syncthreads();

        // DFS merges among subtree roots (M=8 padded to 16), HCUR double-buffered
        int nm = __builtin_ctz(s + 1);
        for (int m = 0; m < nm; ++m){
            --sp;
            const char* hl = HSTK + sp*2048;
            {   // (a) root data sum + bf16 mirror -> XB2[120:128)
                uint32_t row = (uint32_t)(t >> 6), f = (uint32_t)(t & 63);
                float v = *reinterpret_cast<const float*>(DCUR + swz256(row, f*4u))
                        + *reinterpret_cast<const float*>(DSTK + sp*2048 + swz256(row, f*4u));
                *reinterpret_cast<float*>(DCUR + swz256(row, f*4u)) = v;
                *reinterpret_cast<__bf16*>(XB2 + swz128(120u + row, f*2u)) = (__bf16)v;
            }
            __syncthreads();
            // (b) u-merge M=8 -> U[0:16)
            gemm_x<1>(XB2, 120, 8, Ub, 0, wlf, nt, BL);
            __syncthreads();
            // (c) nl-merge -> hc_alt (no in-place hazard; no barrier except last)
            v4f c = (v4f){0,0,0,0};
            #pragma unroll
            for (uint32_t kf = 0; kf < 12; ++kf){
                const char* src = (kf < 4) ? hl : ((kf < 8) ? (const char*)hc_cur
                                                            : (const char*)Ub);
                c = mfma16(ldH(src, kf & 3u), wnl[kf], c);
            }
            epi(hc_alt, 0, c, nt, BN);
            { char* tmp = hc_cur; hc_cur = hc_alt; hc_alt = tmp; }
            if (m == nm - 1) __syncthreads();
        }
    }

    // ---- head: z1 = relu(root@W1+b1) -> U; z2 -> HB; out = z2@W3+b3 ----
    {
        v8bf w1f[4], w2f[4];
        #pragma unroll
        for (int kf = 0; kf < 4; ++kf){
            w1f[kf] = ldW(W1g, kf*32, n0);
            w2f[kf] = ldW(W2g, kf*32, n0);
        }
        {
            v4f c = (v4f){0,0,0,0};
            #pragma unroll
            for (uint32_t kf = 0; kf < 4; ++kf) c = mfma16(ldH(hc_cur, kf), w1f[kf], c);
            epi(Ub, 0, c, nt, B1L);
        }
        __syncthreads();
        {
            v4f c = (v4f){0,0,0,0};
            #pragma unroll
            for (uint32_t kf = 0; kf < 4; ++kf) c = mfma16(ldH(Ub, kf), w2f[kf], c);
            epi(HB, 0, c, nt, B2L);
        }
        __syncthreads();
        if (t < 64){
            float w3a = W3g[t], w3b = W3g[t + 64], b3v = b3g[0];
            #pragma unroll
            for (int r = 0; r < 8; ++r){
                float za = (float)*reinterpret_cast<const __bf16*>(HB + swz256((uint32_t)r, (uint32_t)t*2u));
                float zb = (float)*reinterpret_cast<const __bf16*>(HB + swz256((uint32_t)r, (uint32_t)(t + 64)*2u));
                float v = za*w3a + zb*w3b;
                #pragma unroll
                for (int off = 32; off >= 1; off >>= 1) v += __shfl_xor(v, off, 64);
                if (t == 0) Yg[base + r] = v + b3v;
            }
        }
    }
}

extern "C" void kernel_launch(void* const* d_in, const int* in_sizes, int n_in,
                              void* d_out, int out_size, void* d_ws, size_t ws_size,
                              hipStream_t stream){
    const float* x     = (const float*)d_in[0];
    const float* Wleaf = (const float*)d_in[1];
    const float* bleaf = (const float*)d_in[2];
    const float* Wnl   = (const float*)d_in[3];
    const float* bnl   = (const float*)d_in[4];
    const float* W1    = (const float*)d_in[5];
    const float* b1    = (const float*)d_in[6];
    const float* W2    = (const float*)d_in[7];
    const float* b2    = (const float*)d_in[8];
    const float* W3    = (const float*)d_in[9];
    const float* b3    = (const float*)d_in[10];
    float* out = (float*)d_out;

    recnn_kernel<<<B_TOT/BC, NTHR, 0, stream>>>(x, Wleaf, bleaf, Wnl, bnl,
                                                W1, b1, W2, b2, W3, b3, out);
}